// Round 5
// baseline (862.788 us; speedup 1.0000x reference)
//
#include <hip/hip_runtime.h>

#define HIDD 2048
#define SEQ  2048
#define BATCH 4
#define NHQ  16
#define NKVH 4
#define HDIM 128
#define QKVN 3072   // 2048 Q + 512 K + 512 V

typedef unsigned short u16;
typedef unsigned int   u32;
using bf16x8 = __attribute__((ext_vector_type(8))) __bf16;
using u16x8  = __attribute__((ext_vector_type(8))) u16;
using u16x4  = __attribute__((ext_vector_type(4))) u16;
using f32x4  = __attribute__((ext_vector_type(4))) float;

__device__ __forceinline__ float bf2f(u16 v){ u32 u = ((u32)v) << 16; float f; __builtin_memcpy(&f, &u, 4); return f; }
__device__ __forceinline__ u16 f2bf(float f){ u32 u; __builtin_memcpy(&u, &f, 4); u += 0x7fffu + ((u >> 16) & 1u); return (u16)(u >> 16); }

__device__ __forceinline__ void gl_lds16(const void* g, void* l){
  __builtin_amdgcn_global_load_lds((const __attribute__((address_space(1))) void*)g,
                                   (__attribute__((address_space(3))) void*)l, 16, 0, 0);
}

// ---------------- prep kernels ----------------

__global__ void cvt_f32_bf16(const float* __restrict__ in, u16* __restrict__ out, int n4){
  int i = blockIdx.x * 256 + threadIdx.x;
  if (i >= n4) return;
  float4 v = ((const float4*)in)[i];
  u16x4 o; o[0] = f2bf(v.x); o[1] = f2bf(v.y); o[2] = f2bf(v.z); o[3] = f2bf(v.w);
  ((u16x4*)out)[i] = o;
}

// in: f32 [R][C] -> out: bf16 [C][R]  (out may point into a larger [*][R] buffer)
__global__ void transpose_cvt_f32(const float* __restrict__ in, u16* __restrict__ out, int R, int C){
  __shared__ float t[32][33];
  int c0 = blockIdx.x * 32, r0 = blockIdx.y * 32;
  int tx = threadIdx.x, ty = threadIdx.y;
  #pragma unroll
  for (int i = 0; i < 4; i++)
    t[ty + 8*i][tx] = in[(size_t)(r0 + ty + 8*i) * C + c0 + tx];
  __syncthreads();
  #pragma unroll
  for (int i = 0; i < 4; i++)
    out[(size_t)(c0 + ty + 8*i) * R + r0 + tx] = f2bf(t[tx][ty + 8*i]);
}

// V slice of QKV [B*S][ld] bf16 (cols voff..voff+511) -> Vt [B][NKV][HD][S] bf16
__global__ void transpose_v(const u16* __restrict__ V, u16* __restrict__ Vt, int ld, int voff){
  __shared__ u16 t[32][33];
  int bg = blockIdx.z;
  int b = bg >> 2, g = bg & 3;
  const u16* in = V + (size_t)b * SEQ * ld + voff + g * HDIM;
  u16* out = Vt + (size_t)bg * HDIM * SEQ;
  int c0 = blockIdx.x * 32, r0 = blockIdx.y * 32;   // c: d (0..127), r: s
  int tx = threadIdx.x, ty = threadIdx.y;
  #pragma unroll
  for (int i = 0; i < 4; i++)
    t[ty + 8*i][tx] = in[(size_t)(r0 + ty + 8*i) * ld + c0 + tx];
  __syncthreads();
  #pragma unroll
  for (int i = 0; i < 4; i++)
    out[(size_t)(c0 + ty + 8*i) * SEQ + r0 + tx] = t[tx][ty + 8*i];
}

// in-place RoPE on bf16 rows of a [rows][ld] buffer, covering ncol=2^ncl columns at X.
// cos/sin f32 [S][HD]; scale folded into output (Q: log2e/sqrt(HD)).
__global__ void rope_kernel(u16* __restrict__ X, int ld, int ncl,
                            const float* __restrict__ ct, const float* __restrict__ st,
                            float scale, int n8){
  int i = blockIdx.x * 256 + threadIdx.x;
  if (i >= n8) return;
  int e0 = i * 8;
  int row = e0 >> ncl;
  int col = e0 & ((1 << ncl) - 1);
  int pos = row & (SEQ - 1);
  int dd  = col & (HDIM - 1);
  u16* p = X + (size_t)row * ld + col;
  u16x8 v = *(const u16x8*)p;
  const float* cp = ct + (size_t)pos * HDIM + dd;
  const float* sp = st + (size_t)pos * HDIM + dd;
  float f[8];
  #pragma unroll
  for (int j = 0; j < 8; j++) f[j] = bf2f(v[j]);
  u16x8 o;
  #pragma unroll
  for (int j = 0; j < 8; j += 2){
    float c = cp[j], s = sp[j];        // cos/sin repeated in pairs
    float e = f[j], od = f[j+1];
    o[j]   = f2bf((e * c - od * s) * scale);
    o[j+1] = f2bf((od * c + e * s) * scale);
  }
  *(u16x8*)p = o;
}

// ---------------- GEMM: C[M][N] = A[M][K] * Bt[N][K]^T (bf16 in, f32 acc) ----------------
template<int OUT_BF16>
__global__ __launch_bounds__(256) void gemm_bt(const u16* __restrict__ A, const u16* __restrict__ Bt,
                                               void* __restrict__ Cv, int M, int N, int K){
  __shared__ __align__(16) u16 As[128*32];
  __shared__ __align__(16) u16 Bs[128*32];
  const int tid = threadIdx.x;
  const int wid = tid >> 6, lane = tid & 63;
  const int lr = lane & 15, lk = lane >> 4;
  const int m0 = blockIdx.y * 128, n0 = blockIdx.x * 128;
  const int wr = (wid >> 1) * 64, wc = (wid & 1) * 64;

  f32x4 acc[4][4];
  #pragma unroll
  for (int m = 0; m < 4; m++)
    #pragma unroll
    for (int n = 0; n < 4; n++) acc[m][n] = f32x4{0.f,0.f,0.f,0.f};

  const int srow = lane >> 2;
  const int swz  = ((lane & 3) * 8) ^ ((srow & 3) * 8);
  const u16* Ag = A  + (size_t)(m0 + wid*32 + srow) * K + swz;
  const u16* Bg = Bt + (size_t)(n0 + wid*32 + srow) * K + swz;
  u16* Asl = As + wid * 1024;
  u16* Bsl = Bs + wid * 1024;
  const int rsw = (lr & 3) * 8;

  for (int k0 = 0; k0 < K; k0 += 32){
    gl_lds16(Ag + k0,          Asl);
    gl_lds16(Ag + k0 + 16*K,   Asl + 512);
    gl_lds16(Bg + k0,          Bsl);
    gl_lds16(Bg + k0 + 16*K,   Bsl + 512);
    __syncthreads();
    bf16x8 a[4], b[4];
    #pragma unroll
    for (int m = 0; m < 4; m++) a[m] = *(const bf16x8*)&As[(wr + m*16 + lr)*32 + ((lk*8) ^ rsw)];
    #pragma unroll
    for (int n = 0; n < 4; n++) b[n] = *(const bf16x8*)&Bs[(wc + n*16 + lr)*32 + ((lk*8) ^ rsw)];
    #pragma unroll
    for (int m = 0; m < 4; m++)
      #pragma unroll
      for (int n = 0; n < 4; n++)
        acc[m][n] = __builtin_amdgcn_mfma_f32_16x16x32_bf16(a[m], b[n], acc[m][n], 0, 0, 0);
    __syncthreads();
  }
  #pragma unroll
  for (int m = 0; m < 4; m++)
    #pragma unroll
    for (int n = 0; n < 4; n++)
      #pragma unroll
      for (int i = 0; i < 4; i++){
        int gr = m0 + wr + m*16 + lk*4 + i;
        int gc = n0 + wc + n*16 + lr;
        float v = acc[m][n][i];
        if (OUT_BF16) ((u16*)Cv)[(size_t)gr * N + gc] = f2bf(v);
        else          ((float*)Cv)[(size_t)gr * N + gc] = v;
      }
}

// ---------------- flash attention (no-barrier, L2-direct K/V) ----------------
// 1D grid 1024 blocks, decoded with bijective XCD swizzle so all 64 blocks of a
// (b,g) KV-group land on ONE XCD (2 groups x 1MB KV per 4MB L2).
// Block = 4 independent waves; wave owns 32 q-rows (q0w..q0w+31), iterates its own
// KV-64 tiles with NO __syncthreads. K and V^T fragments are read directly from
// global (L2-served) into registers. Only P goes through (wave-private) LDS.
// Swapped QK: sf[qh][n][i] = S[kv=kv0+n*16+lk*4+i][q=q0w+qh*16+lr]; stats lane-local.
// PV: A=P[q=lr][kv], B=V^T[d=f*16+lr][kv]; oacc[qh][f][i]: q=qh*16+lk*4+i, d=f*16+lr.
__global__ __launch_bounds__(256) void attn_kernel(const u16* __restrict__ QKV, const u16* __restrict__ Vt,
                                                   u16* __restrict__ O){
  const int F = blockIdx.x;
  const int xcd = F & 7, slot = F >> 3;
  const int gi  = xcd + 8 * (slot >> 6);    // 0..15 = b*4+g (KV group)
  const int j   = slot & 63;                // 0..63 within group
  const int b = gi >> 2, g = gi & 3;
  const int h = g * 4 + (j >> 4);
  const int qt = 15 - (j & 15);             // LPT within XCD
  const int tid = threadIdx.x;
  const int wid = tid >> 6, lane = tid & 63;
  const int lr = lane & 15, lk = lane >> 4;
  const int q0w = qt * 128 + wid * 32;      // this wave's first q row

  __shared__ __align__(16) u16 Ps[4][2][16*72];   // per-wave, per-qh P buffers
  u16* Pw0 = &Ps[wid][0][0];
  u16* Pw1 = &Ps[wid][1][0];

  // ---- Q fragments (B operand): lane lr = q-col, k = d = c*32+lk*8 ----
  bf16x8 qf[2][4];
  #pragma unroll
  for (int qh = 0; qh < 2; qh++){
    const u16* qp = QKV + (size_t)(b*SEQ + q0w + qh*16 + lr) * QKVN + h*HDIM + lk*8;
    #pragma unroll
    for (int c = 0; c < 4; c++) qf[qh][c] = *(const bf16x8*)(qp + c*32);
  }

  // ---- per-lane K / V^T bases (L2-direct) ----
  const u16* Kl = QKV + (size_t)b * SEQ * QKVN + HIDD + g*HDIM + (size_t)lr * QKVN + lk*8;
  const u16* Vl = Vt + (size_t)(b*NKVH + g) * HDIM * SEQ + (size_t)lr * SEQ + lk*8;

  f32x4 oacc[2][8];
  #pragma unroll
  for (int qh = 0; qh < 2; qh++)
    #pragma unroll
    for (int f = 0; f < 8; f++) oacc[qh][f] = f32x4{0.f,0.f,0.f,0.f};
  float m_i[2] = {-1e30f, -1e30f}, l_i[2] = {0.f, 0.f};

  const int nt = ((q0w + 31) >> 6) + 1;     // tiles to cover kv <= q0w+31
  for (int t = 0; t < nt; ++t, Kl += 64*QKVN, Vl += 64){
    // ---- K fragments direct from L2: kf[n][c] = K[kv0+n*16+lr][c*32+lk*8..] ----
    bf16x8 kf[4][4];
    #pragma unroll
    for (int n = 0; n < 4; n++)
      #pragma unroll
      for (int c = 0; c < 4; c++)
        kf[n][c] = *(const bf16x8*)(Kl + n*16*QKVN + c*32);

    // ---- swapped QK ----
    f32x4 sf[2][4];
    #pragma unroll
    for (int n = 0; n < 4; n++)
      #pragma unroll
      for (int qh = 0; qh < 2; qh++){
        f32x4 a = f32x4{0.f,0.f,0.f,0.f};
        #pragma unroll
        for (int c = 0; c < 4; c++)
          a = __builtin_amdgcn_mfma_f32_16x16x32_bf16(kf[n][c], qf[qh][c], a, 0, 0, 0);
        sf[qh][n] = a;
      }

    if (t == nt - 1){                       // diagonal tile: causal mask
      const int kv0 = t * 64;
      #pragma unroll
      for (int qh = 0; qh < 2; qh++)
        #pragma unroll
        for (int n = 0; n < 4; n++)
          #pragma unroll
          for (int i = 0; i < 4; i++){
            int kvg = kv0 + n*16 + lk*4 + i;
            int qg  = q0w + qh*16 + lr;
            if (kvg > qg) sf[qh][n][i] = -1e30f;
          }
    }

    // ---- softmax (lane-local stats) + P writes, per qh ----
    #pragma unroll
    for (int qh = 0; qh < 2; qh++){
      u16* Pw = qh ? Pw1 : Pw0;
      float rm = sf[qh][0][0];
      #pragma unroll
      for (int n = 0; n < 4; n++)
        #pragma unroll
        for (int i = 0; i < 4; i++) rm = fmaxf(rm, sf[qh][n][i]);
      rm = fmaxf(rm, __shfl_xor(rm, 16));
      rm = fmaxf(rm, __shfl_xor(rm, 32));

      if (!__all(rm <= m_i[qh] + 11.5f)){   // defer-max: rescale is rare
        float mn = fmaxf(m_i[qh], rm);
        float cf = exp2f(m_i[qh] - mn);
        m_i[qh] = mn; l_i[qh] *= cf;
        float cfq[4];
        #pragma unroll
        for (int i = 0; i < 4; i++) cfq[i] = __shfl(cf, lk*4 + i);
        #pragma unroll
        for (int f = 0; f < 8; f++)
          #pragma unroll
          for (int i = 0; i < 4; i++) oacc[qh][f][i] *= cfq[i];
      }
      float rs = 0.f;
      #pragma unroll
      for (int n = 0; n < 4; n++){
        u16x4 pp;
        #pragma unroll
        for (int i = 0; i < 4; i++){
          float pv = exp2f(sf[qh][n][i] - m_i[qh]);
          rs += pv;
          pp[i] = f2bf(pv);
        }
        *(u16x4*)&Pw[lr*72 + n*16 + lk*4] = pp;   // ds_write_b64
      }
      rs += __shfl_xor(rs, 16);
      rs += __shfl_xor(rs, 32);
      l_i[qh] += rs;
    }

    // ---- PV: V^T fragments direct from L2, shared across both qh ----
    #pragma unroll
    for (int kc = 0; kc < 2; kc++){
      bf16x8 vf[8];
      #pragma unroll
      for (int f = 0; f < 8; f++)
        vf[f] = *(const bf16x8*)(Vl + f*16*SEQ + kc*32);
      bf16x8 pf0 = *(const bf16x8*)&Pw0[lr*72 + kc*32 + lk*8];
      bf16x8 pf1 = *(const bf16x8*)&Pw1[lr*72 + kc*32 + lk*8];
      #pragma unroll
      for (int f = 0; f < 8; f++){
        oacc[0][f] = __builtin_amdgcn_mfma_f32_16x16x32_bf16(pf0, vf[f], oacc[0][f], 0, 0, 0);
        oacc[1][f] = __builtin_amdgcn_mfma_f32_16x16x32_bf16(pf1, vf[f], oacc[1][f], 0, 0, 0);
      }
    }
  }

  // ---- epilogue: O[b][q][h*128 + d] bf16; l broadcast lr -> lk*4+i ----
  #pragma unroll
  for (int qh = 0; qh < 2; qh++){
    float linv[4];
    #pragma unroll
    for (int i = 0; i < 4; i++) linv[i] = 1.0f / __shfl(l_i[qh], lk*4 + i);
    #pragma unroll
    for (int f = 0; f < 8; f++)
      #pragma unroll
      for (int i = 0; i < 4; i++){
        int qr = q0w + qh*16 + lk*4 + i;
        O[(size_t)(b*SEQ + qr) * (NHQ*HDIM) + h*HDIM + f*16 + lr] = f2bf(oacc[qh][f][i] * linv[i]);
      }
  }
}

// ---------------- launch ----------------

extern "C" void kernel_launch(void* const* d_in, const int* in_sizes, int n_in,
                              void* d_out, int out_size, void* d_ws, size_t ws_size,
                              hipStream_t stream){
  const float* x    = (const float*)d_in[0];
  const float* cosb = (const float*)d_in[1];
  const float* sinb = (const float*)d_in[2];
  const float* wq   = (const float*)d_in[3];
  const float* wk   = (const float*)d_in[4];
  const float* wv   = (const float*)d_in[5];
  const float* wo   = (const float*)d_in[6];
  float* out = (float*)d_out;

  char* ws = (char*)d_ws;
  u16* XB    = (u16*)(ws);                    // 32 MB: x bf16; later attention output O
  u16* WQKVT = (u16*)(ws + 33554432);         // 12.6 MB: [3072][2048] (Q rows 0..2047, K 2048..2559, V 2560..3071)
  u16* WOT   = (u16*)(ws + 46137344);         // 8 MB
  u16* QKV   = (u16*)(ws + 54525952);         // 50.3 MB: [8192][3072]
  u16* VT    = (u16*)(ws + 104857600);        // 8 MB   (end: 113246208)

  dim3 tb(32, 8);
  // x -> bf16
  cvt_f32_bf16<<<(BATCH*SEQ*HIDD/4 + 255)/256, 256, 0, stream>>>(x, XB, BATCH*SEQ*HIDD/4);
  // weights -> bf16 transposed, fused QKV weight [3072][2048]
  transpose_cvt_f32<<<dim3(HIDD/32, HIDD/32), tb, 0, stream>>>(wq, WQKVT, HIDD, NHQ*HDIM);
  transpose_cvt_f32<<<dim3((NKVH*HDIM)/32, HIDD/32), tb, 0, stream>>>(wk, WQKVT + (size_t)2048*2048, HIDD, NKVH*HDIM);
  transpose_cvt_f32<<<dim3((NKVH*HDIM)/32, HIDD/32), tb, 0, stream>>>(wv, WQKVT + (size_t)2560*2048, HIDD, NKVH*HDIM);
  transpose_cvt_f32<<<dim3(HIDD/32, HIDD/32), tb, 0, stream>>>(wo, WOT, NHQ*HDIM, HIDD);
  // fused QKV projection: [8192][3072]
  gemm_bt<1><<<dim3(QKVN/128, BATCH*SEQ/128), 256, 0, stream>>>(XB, WQKVT, QKV, BATCH*SEQ, QKVN, HIDD);
  // RoPE: Q cols (scale = log2e/sqrt(128)), K cols (scale 1)
  rope_kernel<<<(BATCH*SEQ*2048/8)/256, 256, 0, stream>>>(QKV, QKVN, 11, cosb, sinb, 0.12753165651003169f, BATCH*SEQ*2048/8);
  rope_kernel<<<(BATCH*SEQ*512/8)/256, 256, 0, stream>>>(QKV + HIDD, QKVN, 9, cosb, sinb, 1.0f, BATCH*SEQ*512/8);
  // V -> [B][NKV][HD][S]
  transpose_v<<<dim3(HDIM/32, SEQ/32, BATCH*NKVH), tb, 0, stream>>>(QKV, VT, QKVN, 2560);
  // attention (writes O into XB region)
  attn_kernel<<<dim3(SEQ/128 * NHQ * BATCH), 256, 0, stream>>>(QKV, VT, XB);
  // out projection (f32 out)
  gemm_bt<0><<<dim3(HIDD/128, BATCH*SEQ/128), 256, 0, stream>>>(XB, WOT, out, BATCH*SEQ, HIDD, NHQ*HDIM);
}

// Round 6
// 618.253 us; speedup vs baseline: 1.3955x; 1.3955x over previous
//
#include <hip/hip_runtime.h>

#define HIDD 2048
#define SEQ  2048
#define BATCH 4
#define NHQ  16
#define NKVH 4
#define HDIM 128
#define QKVN 3072   // 2048 Q + 512 K + 512 V

typedef unsigned short u16;
typedef unsigned int   u32;
using bf16x8 = __attribute__((ext_vector_type(8))) __bf16;
using u16x8  = __attribute__((ext_vector_type(8))) u16;
using u16x4  = __attribute__((ext_vector_type(4))) u16;
using f32x4  = __attribute__((ext_vector_type(4))) float;

__device__ __forceinline__ float bf2f(u16 v){ u32 u = ((u32)v) << 16; float f; __builtin_memcpy(&f, &u, 4); return f; }
__device__ __forceinline__ u16 f2bf(float f){ u32 u; __builtin_memcpy(&u, &f, 4); u += 0x7fffu + ((u >> 16) & 1u); return (u16)(u >> 16); }

__device__ __forceinline__ void gl_lds16(const void* g, void* l){
  __builtin_amdgcn_global_load_lds((const __attribute__((address_space(1))) void*)g,
                                   (__attribute__((address_space(3))) void*)l, 16, 0, 0);
}

// ---------------- prep kernels ----------------

__global__ void cvt_f32_bf16(const float* __restrict__ in, u16* __restrict__ out, int n4){
  int i = blockIdx.x * 256 + threadIdx.x;
  if (i >= n4) return;
  float4 v = ((const float4*)in)[i];
  u16x4 o; o[0] = f2bf(v.x); o[1] = f2bf(v.y); o[2] = f2bf(v.z); o[3] = f2bf(v.w);
  ((u16x4*)out)[i] = o;
}

// in: f32 [R][C] -> out: bf16 [C][R]  (out may point into a larger [*][R] buffer)
__global__ void transpose_cvt_f32(const float* __restrict__ in, u16* __restrict__ out, int R, int C){
  __shared__ float t[32][33];
  int c0 = blockIdx.x * 32, r0 = blockIdx.y * 32;
  int tx = threadIdx.x, ty = threadIdx.y;
  #pragma unroll
  for (int i = 0; i < 4; i++)
    t[ty + 8*i][tx] = in[(size_t)(r0 + ty + 8*i) * C + c0 + tx];
  __syncthreads();
  #pragma unroll
  for (int i = 0; i < 4; i++)
    out[(size_t)(c0 + ty + 8*i) * R + r0 + tx] = f2bf(t[tx][ty + 8*i]);
}

// V slice of QKV [B*S][ld] bf16 (cols voff..voff+511) -> Vt [B][NKV][HD][S] bf16
__global__ void transpose_v(const u16* __restrict__ V, u16* __restrict__ Vt, int ld, int voff){
  __shared__ u16 t[32][33];
  int bg = blockIdx.z;
  int b = bg >> 2, g = bg & 3;
  const u16* in = V + (size_t)b * SEQ * ld + voff + g * HDIM;
  u16* out = Vt + (size_t)bg * HDIM * SEQ;
  int c0 = blockIdx.x * 32, r0 = blockIdx.y * 32;   // c: d (0..127), r: s
  int tx = threadIdx.x, ty = threadIdx.y;
  #pragma unroll
  for (int i = 0; i < 4; i++)
    t[ty + 8*i][tx] = in[(size_t)(r0 + ty + 8*i) * ld + c0 + tx];
  __syncthreads();
  #pragma unroll
  for (int i = 0; i < 4; i++)
    out[(size_t)(c0 + ty + 8*i) * SEQ + r0 + tx] = t[tx][ty + 8*i];
}

// in-place RoPE on bf16 rows of a [rows][ld] buffer, covering ncol=2^ncl columns at X.
// cos/sin f32 [S][HD]; scale folded into output (Q: log2e/sqrt(HD)).
__global__ void rope_kernel(u16* __restrict__ X, int ld, int ncl,
                            const float* __restrict__ ct, const float* __restrict__ st,
                            float scale, int n8){
  int i = blockIdx.x * 256 + threadIdx.x;
  if (i >= n8) return;
  int e0 = i * 8;
  int row = e0 >> ncl;
  int col = e0 & ((1 << ncl) - 1);
  int pos = row & (SEQ - 1);
  int dd  = col & (HDIM - 1);
  u16* p = X + (size_t)row * ld + col;
  u16x8 v = *(const u16x8*)p;
  const float* cp = ct + (size_t)pos * HDIM + dd;
  const float* sp = st + (size_t)pos * HDIM + dd;
  float f[8];
  #pragma unroll
  for (int j = 0; j < 8; j++) f[j] = bf2f(v[j]);
  u16x8 o;
  #pragma unroll
  for (int j = 0; j < 8; j += 2){
    float c = cp[j], s = sp[j];        // cos/sin repeated in pairs
    float e = f[j], od = f[j+1];
    o[j]   = f2bf((e * c - od * s) * scale);
    o[j+1] = f2bf((od * c + e * s) * scale);
  }
  *(u16x8*)p = o;
}

// ---------------- GEMM: C[M][N] = A[M][K] * Bt[N][K]^T (bf16 in, f32 acc) ----------------
template<int OUT_BF16>
__global__ __launch_bounds__(256) void gemm_bt(const u16* __restrict__ A, const u16* __restrict__ Bt,
                                               void* __restrict__ Cv, int M, int N, int K){
  __shared__ __align__(16) u16 As[128*32];
  __shared__ __align__(16) u16 Bs[128*32];
  const int tid = threadIdx.x;
  const int wid = tid >> 6, lane = tid & 63;
  const int lr = lane & 15, lk = lane >> 4;
  const int m0 = blockIdx.y * 128, n0 = blockIdx.x * 128;
  const int wr = (wid >> 1) * 64, wc = (wid & 1) * 64;

  f32x4 acc[4][4];
  #pragma unroll
  for (int m = 0; m < 4; m++)
    #pragma unroll
    for (int n = 0; n < 4; n++) acc[m][n] = f32x4{0.f,0.f,0.f,0.f};

  const int srow = lane >> 2;
  const int swz  = ((lane & 3) * 8) ^ ((srow & 3) * 8);
  const u16* Ag = A  + (size_t)(m0 + wid*32 + srow) * K + swz;
  const u16* Bg = Bt + (size_t)(n0 + wid*32 + srow) * K + swz;
  u16* Asl = As + wid * 1024;
  u16* Bsl = Bs + wid * 1024;
  const int rsw = (lr & 3) * 8;

  for (int k0 = 0; k0 < K; k0 += 32){
    gl_lds16(Ag + k0,          Asl);
    gl_lds16(Ag + k0 + 16*K,   Asl + 512);
    gl_lds16(Bg + k0,          Bsl);
    gl_lds16(Bg + k0 + 16*K,   Bsl + 512);
    __syncthreads();
    bf16x8 a[4], b[4];
    #pragma unroll
    for (int m = 0; m < 4; m++) a[m] = *(const bf16x8*)&As[(wr + m*16 + lr)*32 + ((lk*8) ^ rsw)];
    #pragma unroll
    for (int n = 0; n < 4; n++) b[n] = *(const bf16x8*)&Bs[(wc + n*16 + lr)*32 + ((lk*8) ^ rsw)];
    #pragma unroll
    for (int m = 0; m < 4; m++)
      #pragma unroll
      for (int n = 0; n < 4; n++)
        acc[m][n] = __builtin_amdgcn_mfma_f32_16x16x32_bf16(a[m], b[n], acc[m][n], 0, 0, 0);
    __syncthreads();
  }
  #pragma unroll
  for (int m = 0; m < 4; m++)
    #pragma unroll
    for (int n = 0; n < 4; n++)
      #pragma unroll
      for (int i = 0; i < 4; i++){
        int gr = m0 + wr + m*16 + lk*4 + i;
        int gc = n0 + wc + n*16 + lr;
        float v = acc[m][n][i];
        if (OUT_BF16) ((u16*)Cv)[(size_t)gr * N + gc] = f2bf(v);
        else          ((float*)Cv)[(size_t)gr * N + gc] = v;
      }
}

// ---------------- flash attention (swapped-QK, paired q-tiles, uniform work) ----------------
// grid: (8, NH, B) = 512 blocks, block 256 = 4 waves x 32 q-rows.
// Block p processes q-tile (15-p) then q-tile p (128 q-rows each):
//   per-block kv-tile iterations = 2*(16-p) + 2*(p+1) = 34 for EVERY block ->
//   perfectly uniform static schedule, exactly 2 blocks/CU (LDS 74.75KB) -> no tail.
// Q pre-scaled by log2e/sqrt(HD). K/V double-buffered linear LDS via global_load_lds w16,
// inverse-XOR-swizzled global source; reads XOR-swizzle (chunk ^= row&7).
// Swapped QK: sf[qh][n][i] = S[kv=kv0+n*16+lk*4+i][q=q0w+qh*16+lr]; stats lane-local.
// PV un-swapped: P via per-wave LDS (A), V^T from LDS (B); oacc[qh][f][i]: q=qh*16+lk*4+i, d=f*16+lr.
__global__ __launch_bounds__(256) void attn_kernel(const u16* __restrict__ QKV, const u16* __restrict__ Vt,
                                                   u16* __restrict__ O){
  const int p = blockIdx.x;                         // 0..7 pair index
  const int h = blockIdx.y, b = blockIdx.z;
  const int g = h >> 2;
  const int tid = threadIdx.x;
  const int wid = tid >> 6, lane = tid & 63;
  const int lr = lane & 15, lk = lane >> 4;

  __shared__ __align__(16) u16 Ks[2][64*128];       // linear, contents chunk-swizzled by row&7
  __shared__ __align__(16) u16 Vs[2][128*64];
  __shared__ __align__(16) u16 Ps[4][16*72];        // per-wave P buffer (reused across qh)
  u16* Pw = &Ps[wid][0];

  // ---- staging base pointers (per-lane swizzled global src, wave-uniform LDS dest) ----
  const int klr = lane >> 4, kj = lane & 15;        // K: 4 rows x 16 chunks per 1KB block
  const int vlr = lane >> 3, vj = lane & 7;         // V: 8 rows x 8 chunks per 1KB block
  const u16* Kst0[4]; const u16* Vst0[4];
  {
    const u16* Kbase = QKV + (size_t)b * SEQ * QKVN + HIDD + g*HDIM;
    const u16* Vbase = Vt + (size_t)(b*NKVH + g) * HDIM * SEQ;
    #pragma unroll
    for (int iw = 0; iw < 4; iw++){
      int kcb = wid*4 + iw;
      int r   = kcb*4 + klr;
      Kst0[iw] = Kbase + (size_t)r * QKVN + ((kj ^ (r & 7)) << 3);
      int d   = kcb*8 + vlr;
      Vst0[iw] = Vbase + (size_t)d * SEQ + ((vj ^ (d & 7)) << 3);
    }
  }

  for (int seg = 0; seg < 2; ++seg){
    const int qt  = seg ? p : (15 - p);
    const int q0w = qt * 128 + wid * 32;            // this wave's first q row

    // ---- Q fragments (B operand): lane lr = q-col, k = d = c*32+lk*8 ----
    bf16x8 qf[2][4];
    #pragma unroll
    for (int qh = 0; qh < 2; qh++){
      const u16* qp = QKV + (size_t)(b*SEQ + q0w + qh*16 + lr) * QKVN + h*HDIM + lk*8;
      #pragma unroll
      for (int c = 0; c < 4; c++) qf[qh][c] = *(const bf16x8*)(qp + c*32);
    }

    const u16* Kl[4]; const u16* Vl[4];
    #pragma unroll
    for (int iw = 0; iw < 4; iw++){ Kl[iw] = Kst0[iw]; Vl[iw] = Vst0[iw]; }

    f32x4 oacc[2][8];
    #pragma unroll
    for (int qh = 0; qh < 2; qh++)
      #pragma unroll
      for (int f = 0; f < 8; f++) oacc[qh][f] = f32x4{0.f,0.f,0.f,0.f};
    float m_i[2] = {-1e30f, -1e30f}, l_i[2] = {0.f, 0.f};

    __syncthreads();                    // protect LDS buffers from previous segment's readers

    const int nt = 2 * (qt + 1);
    int cur = 0;
    // prologue: stage tile 0 into buf 0
    #pragma unroll
    for (int iw = 0; iw < 4; iw++){
      int kcb = wid*4 + iw;
      gl_lds16(Kl[iw], &Ks[0][kcb << 9]);
      gl_lds16(Vl[iw], &Vs[0][kcb << 9]);
      Kl[iw] += 64 * QKVN;
      Vl[iw] += 64;
    }

    for (int t = 0; t < nt; ++t){
      __syncthreads();                  // stage(cur) drained (vmcnt0 before barrier)
      if (t + 1 < nt){
        #pragma unroll
        for (int iw = 0; iw < 4; iw++){
          int kcb = wid*4 + iw;
          gl_lds16(Kl[iw], &Ks[cur ^ 1][kcb << 9]);
          gl_lds16(Vl[iw], &Vs[cur ^ 1][kcb << 9]);
          Kl[iw] += 64 * QKVN;
          Vl[iw] += 64;
        }
      }
      const int kv0 = t * 64;
      if (kv0 <= q0w + 31){             // wave has at least one unmasked row this tile
        // ---- swapped QK: sf[qh][n][i] = S[kv=n*16+lk*4+i][q=qh*16+lr] ----
        f32x4 sf[2][4];
        #pragma unroll
        for (int n = 0; n < 4; n++){
          bf16x8 kf[4];
          #pragma unroll
          for (int c = 0; c < 4; c++)
            kf[c] = *(const bf16x8*)&Ks[cur][(n*16 + lr)*128 + (((c*4 + lk) ^ (lr & 7)) << 3)];
          #pragma unroll
          for (int qh = 0; qh < 2; qh++){
            f32x4 a = f32x4{0.f,0.f,0.f,0.f};
            #pragma unroll
            for (int c = 0; c < 4; c++)
              a = __builtin_amdgcn_mfma_f32_16x16x32_bf16(kf[c], qf[qh][c], a, 0, 0, 0);
            sf[qh][n] = a;
          }
        }
        if (kv0 + 63 > q0w){            // tile overlaps diagonal for this wave
          #pragma unroll
          for (int qh = 0; qh < 2; qh++)
            #pragma unroll
            for (int n = 0; n < 4; n++)
              #pragma unroll
              for (int i = 0; i < 4; i++){
                int kvg = kv0 + n*16 + lk*4 + i;
                int qg  = q0w + qh*16 + lr;
                if (kvg > qg) sf[qh][n][i] = -1e30f;
              }
        }
        // ---- per-qh: in-lane softmax + PV ----
        #pragma unroll
        for (int qh = 0; qh < 2; qh++){
          float rm = sf[qh][0][0];
          #pragma unroll
          for (int n = 0; n < 4; n++)
            #pragma unroll
            for (int i = 0; i < 4; i++) rm = fmaxf(rm, sf[qh][n][i]);
          rm = fmaxf(rm, __shfl_xor(rm, 16));
          rm = fmaxf(rm, __shfl_xor(rm, 32));

          if (!__all(rm <= m_i[qh] + 11.5f)){      // defer-max: rescale is rare
            float mn = fmaxf(m_i[qh], rm);
            float cf = exp2f(m_i[qh] - mn);
            m_i[qh] = mn; l_i[qh] *= cf;
            float cfq[4];
            #pragma unroll
            for (int i = 0; i < 4; i++) cfq[i] = __shfl(cf, lk*4 + i);
            #pragma unroll
            for (int f = 0; f < 8; f++)
              #pragma unroll
              for (int i = 0; i < 4; i++) oacc[qh][f][i] *= cfq[i];
          }
          float rs = 0.f;
          #pragma unroll
          for (int n = 0; n < 4; n++){
            u16x4 pp;
            #pragma unroll
            for (int i = 0; i < 4; i++){
              float pv = exp2f(sf[qh][n][i] - m_i[qh]);
              rs += pv;
              pp[i] = f2bf(pv);
            }
            *(u16x4*)&Pw[lr*72 + n*16 + lk*4] = pp; // ds_write_b64, kv-contiguous
          }
          rs += __shfl_xor(rs, 16);
          rs += __shfl_xor(rs, 32);
          l_i[qh] += rs;

          // PV: A = P[q=lr][kv], B = V^T[d=f*16+lr][kv]
          #pragma unroll
          for (int kc = 0; kc < 2; kc++){
            bf16x8 pf = *(const bf16x8*)&Pw[lr*72 + kc*32 + lk*8];
            #pragma unroll
            for (int f = 0; f < 8; f++){
              bf16x8 vf = *(const bf16x8*)&Vs[cur][(f*16 + lr)*64 + (((kc*4 + lk) ^ (lr & 7)) << 3)];
              oacc[qh][f] = __builtin_amdgcn_mfma_f32_16x16x32_bf16(pf, vf, oacc[qh][f], 0, 0, 0);
            }
          }
        }
      }
      cur ^= 1;
    }
    // ---- epilogue: O[b][q][h*128 + d] bf16; l broadcast lr -> lk*4+i ----
    #pragma unroll
    for (int qh = 0; qh < 2; qh++){
      float linv[4];
      #pragma unroll
      for (int i = 0; i < 4; i++) linv[i] = 1.0f / __shfl(l_i[qh], lk*4 + i);
      #pragma unroll
      for (int f = 0; f < 8; f++)
        #pragma unroll
        for (int i = 0; i < 4; i++){
          int qr = q0w + qh*16 + lk*4 + i;
          O[(size_t)(b*SEQ + qr) * (NHQ*HDIM) + h*HDIM + f*16 + lr] = f2bf(oacc[qh][f][i] * linv[i]);
        }
    }
  }
}

// ---------------- launch ----------------

extern "C" void kernel_launch(void* const* d_in, const int* in_sizes, int n_in,
                              void* d_out, int out_size, void* d_ws, size_t ws_size,
                              hipStream_t stream){
  const float* x    = (const float*)d_in[0];
  const float* cosb = (const float*)d_in[1];
  const float* sinb = (const float*)d_in[2];
  const float* wq   = (const float*)d_in[3];
  const float* wk   = (const float*)d_in[4];
  const float* wv   = (const float*)d_in[5];
  const float* wo   = (const float*)d_in[6];
  float* out = (float*)d_out;

  char* ws = (char*)d_ws;
  u16* XB    = (u16*)(ws);                    // 32 MB: x bf16; later attention output O
  u16* WQKVT = (u16*)(ws + 33554432);         // 12.6 MB: [3072][2048] (Q rows 0..2047, K 2048..2559, V 2560..3071)
  u16* WOT   = (u16*)(ws + 46137344);         // 8 MB
  u16* QKV   = (u16*)(ws + 54525952);         // 50.3 MB: [8192][3072]
  u16* VT    = (u16*)(ws + 104857600);        // 8 MB   (end: 113246208)

  dim3 tb(32, 8);
  // x -> bf16
  cvt_f32_bf16<<<(BATCH*SEQ*HIDD/4 + 255)/256, 256, 0, stream>>>(x, XB, BATCH*SEQ*HIDD/4);
  // weights -> bf16 transposed, fused QKV weight [3072][2048]
  transpose_cvt_f32<<<dim3(HIDD/32, HIDD/32), tb, 0, stream>>>(wq, WQKVT, HIDD, NHQ*HDIM);
  transpose_cvt_f32<<<dim3((NKVH*HDIM)/32, HIDD/32), tb, 0, stream>>>(wk, WQKVT + (size_t)2048*2048, HIDD, NKVH*HDIM);
  transpose_cvt_f32<<<dim3((NKVH*HDIM)/32, HIDD/32), tb, 0, stream>>>(wv, WQKVT + (size_t)2560*2048, HIDD, NKVH*HDIM);
  transpose_cvt_f32<<<dim3(HIDD/32, HIDD/32), tb, 0, stream>>>(wo, WOT, NHQ*HDIM, HIDD);
  // fused QKV projection: [8192][3072]
  gemm_bt<1><<<dim3(QKVN/128, BATCH*SEQ/128), 256, 0, stream>>>(XB, WQKVT, QKV, BATCH*SEQ, QKVN, HIDD);
  // RoPE: Q cols (scale = log2e/sqrt(128)), K cols (scale 1)
  rope_kernel<<<(BATCH*SEQ*2048/8)/256, 256, 0, stream>>>(QKV, QKVN, 11, cosb, sinb, 0.12753165651003169f, BATCH*SEQ*2048/8);
  rope_kernel<<<(BATCH*SEQ*512/8)/256, 256, 0, stream>>>(QKV + HIDD, QKVN, 9, cosb, sinb, 1.0f, BATCH*SEQ*512/8);
  // V -> [B][NKV][HD][S]
  transpose_v<<<dim3(HDIM/32, SEQ/32, BATCH*NKVH), tb, 0, stream>>>(QKV, VT, QKVN, 2560);
  // attention (writes O into XB region)
  attn_kernel<<<dim3(8, NHQ, BATCH), 256, 0, stream>>>(QKV, VT, XB);
  // out projection (f32 out)
  gemm_bt<0><<<dim3(HIDD/128, BATCH*SEQ/128), 256, 0, stream>>>(XB, WOT, out, BATCH*SEQ, HIDD, NHQ*HDIM);
}